// Round 3
// baseline (2589.046 us; speedup 1.0000x reference)
//
#include <hip/hip_runtime.h>
#include <math.h>
#include <string.h>

#define PI_D 3.14159265358979323846264338327950288

// ---------------------------------------------------------------------------
// Scattering2D (J=4, L=8, 256x256, B=16) + MLP, all fp32.
// 2D FFT = row-Stockham-FFT-with-transposed-write applied twice.
// Subsampling is done as spectrum folding fused into pass-1 load.
// fold8_kernel: reads each source spectrum row ONCE and folds through all
// 8 orientation filters at once (R2 profile: per-l2 MULFOLD re-read the
// full spectrum 8x -> ~1.5 GB redundant logical traffic).
// ---------------------------------------------------------------------------

enum { IN_COMPLEX = 0, IN_REAL = 1, IN_MULFOLD = 2 };
enum { OUT_COMPLEX = 0, OUT_ABS = 1, OUT_REAL_S = 2 };

struct RftParams {
  const float2* srcC;
  const float*  srcR;
  const float*  filt;
  float2* dstC;
  float*  dstR;
  int m1;        // source resolution for MULFOLD
  int srcDiv;    // source image = img / srcDiv
  int filtMod;   // filter index = img % filtMod
  float scale;   // ifft scale (1/m1^2), applied at load
  float sign;    // -1 forward, +1 inverse
  int chDiv, chBase, b0;   // S-write addressing
  int inMode, outMode;
};

template<int M>
__global__ __launch_bounds__(256) void rft_kernel(RftParams p) {
  constexpr int R = (M >= 64) ? 8 : ((M == 32) ? 16 : 32);   // rows per block
  constexpr int T = (M == 16) ? 4 : ((M == 32) ? 5 : ((M == 64) ? 6 : ((M == 128) ? 7 : 8)));
  __shared__ float2 Abuf[R][M + 1];
  __shared__ float2 Bbuf[R][M + 1];
  __shared__ float2 W[M / 2];
  const int tid = threadIdx.x;
  const long rows0 = (long)blockIdx.x * R;

  // twiddle table: W[q] = exp(sign * 2*pi*i * q / M)
  {
    const float base = p.sign * 6.28318530717958647692f / (float)M;
    for (int i = tid; i < M / 2; i += 256) {
      float sv, cv;
      sincosf(base * (float)i, &sv, &cv);
      W[i] = make_float2(cv, sv);
    }
  }

  // ---- load R rows of length M into Abuf ----
  if (p.inMode == IN_COMPLEX) {
    const float2* s = p.srcC + rows0 * M;
    for (int idx = tid; idx < R * M; idx += 256)
      Abuf[idx / M][idx % M] = s[idx];
  } else if (p.inMode == IN_REAL) {
    const float* s = p.srcR + rows0 * M;
    for (int idx = tid; idx < R * M; idx += 256)
      Abuf[idx / M][idx % M] = make_float2(s[idx], 0.f);
  } else {  // IN_MULFOLD: spectrum * filter, folded from m1^2 down to M^2
    const int m1 = p.m1;
    const int k = m1 / M;
    for (int idx = tid; idx < R * M; idx += 256) {
      const int rl = idx / M, c = idx % M;
      const long g = rows0 + rl;
      const long img = g / M;
      const int r = (int)(g - img * M);
      const float2* sp = p.srcC + (img / p.srcDiv) * (long)m1 * m1;
      const float* fp = p.filt + (long)(img % p.filtMod) * m1 * m1;
      float re = 0.f, im = 0.f;
      for (int qr = 0; qr < k; qr++) {
        const long ro = (long)(r + qr * M) * m1;
        const float2* srow = sp + ro;
        const float*  frow = fp + ro;
        for (int qc = 0; qc < k; qc++) {
          const int cc = c + qc * M;
          const float2 v = srow[cc];
          const float fv = frow[cc];
          re = fmaf(v.x, fv, re);
          im = fmaf(v.y, fv, im);
        }
      }
      Abuf[rl][c] = make_float2(re * p.scale, im * p.scale);
    }
  }
  __syncthreads();

  // ---- Stockham radix-2 DIF (autosort), T stages, ping-pong A<->B ----
  #pragma unroll
  for (int t = 0; t < T; t++) {
    const int s = 1 << t;
    float2 (*Src)[M + 1] = (t & 1) ? Bbuf : Abuf;
    float2 (*Dst)[M + 1] = (t & 1) ? Abuf : Bbuf;
    for (int bf = tid; bf < R * (M / 2); bf += 256) {
      const int row = bf / (M / 2);
      const int j = bf - row * (M / 2);
      const float2 a = Src[row][j];
      const float2 b = Src[row][j + M / 2];
      const float2 w = W[j & ~(s - 1)];
      const float vx = a.x - b.x, vy = a.y - b.y;
      const int dc = (j & (s - 1)) + ((j >> t) << (t + 1));
      Dst[row][dc] = make_float2(a.x + b.x, a.y + b.y);
      Dst[row][dc + s] = make_float2(vx * w.x - vy * w.y, vx * w.y + vy * w.x);
    }
    __syncthreads();
  }
  float2 (*P)[M + 1] = (T & 1) ? Bbuf : Abuf;

  // ---- store transposed: out[img][fo][rpos] = FFT(row rpos)[fo] ----
  if (p.outMode == OUT_COMPLEX) {
    for (int idx = tid; idx < R * M; idx += 256) {
      const int rl = idx & (R - 1);
      const int fo = idx / R;
      const long g = rows0 + rl;
      const long img = g / M;
      const int rpos = (int)(g - img * M);
      p.dstC[img * (long)M * M + (long)fo * M + rpos] = P[rl][fo];
    }
  } else if (p.outMode == OUT_ABS) {
    for (int idx = tid; idx < R * M; idx += 256) {
      const int rl = idx & (R - 1);
      const int fo = idx / R;
      const long g = rows0 + rl;
      const long img = g / M;
      const int rpos = (int)(g - img * M);
      const float2 z = P[rl][fo];
      p.dstR[img * (long)M * M + (long)fo * M + rpos] = sqrtf(z.x * z.x + z.y * z.y);
    }
  } else {  // OUT_REAL_S (M == 16): scatter Re into S[b][ch][16][16]
    for (int idx = tid; idx < R * M; idx += 256) {
      const int rl = idx & (R - 1);
      const int fo = idx / R;
      const long g = rows0 + rl;
      const long img = g / M;
      const int rpos = (int)(g - img * M);
      const int bidx = (int)(img / p.chDiv) + p.b0;
      const int ch = p.chBase + (int)(img % p.chDiv);
      p.dstR[((long)bidx * 417 + ch) * 256 + fo * M + rpos] = P[rl][fo].x;
    }
  }
}

static void rft_go(int M, int nimg, const RftParams& p, hipStream_t st) {
  const int R = (M >= 64) ? 8 : ((M == 32) ? 16 : 32);
  const int blocks = nimg * M / R;
  switch (M) {
    case 256: rft_kernel<256><<<blocks, 256, 0, st>>>(p); break;
    case 128: rft_kernel<128><<<blocks, 256, 0, st>>>(p); break;
    case  64: rft_kernel< 64><<<blocks, 256, 0, st>>>(p); break;
    case  32: rft_kernel< 32><<<blocks, 256, 0, st>>>(p); break;
    case  16: rft_kernel< 16><<<blocks, 256, 0, st>>>(p); break;
  }
}

// ---------------------------------------------------------------------------
// fold8: for each source spectrum (m1 x m1) produce, for ALL 8 filters of a
// psi bank, the folded (M2 x M2) spectrum and its ifft pass-1, in one kernel.
// Spectrum rows are read exactly once (staged in LDS); filters are L2-hot.
// Fold accumulation order (qr outer, qc inner) matches rft IN_MULFOLD
// bitwise. Output layout identical to rft pass-1 OUT_COMPLEX.
// ---------------------------------------------------------------------------
struct Fold8Params {
  const float2* srcC;  // nsrc images, m1*m1
  const float*  filt;  // 8 filters, m1*m1
  float2* dstC;        // nsrc*8 images, M2*M2 (pass-1 transposed layout)
  int m1;
  float scale;
};

template<int M2>
__global__ __launch_bounds__(256) void fold8_kernel(Fold8Params p) {
  constexpr int R = 8;
  constexpr int T = (M2 == 32) ? 5 : ((M2 == 64) ? 6 : 7);
  constexpr int G = 256 / M2;     // thread groups over l2: 8,4,2
  constexpr int LP = 8 / G;       // l2 per thread: 1,2,4
  __shared__ float2 srow[8][256];          // up to k(<=8) staged source rows
  __shared__ float2 Abuf[R][M2 + 1];
  __shared__ float2 Bbuf[R][M2 + 1];
  __shared__ float2 W[M2 / 2];
  const int tid = threadIdx.x;
  const int nrg = M2 / R;
  const int s   = blockIdx.x / nrg;
  const int rg  = blockIdx.x % nrg;
  const int m1  = p.m1;
  const int k   = m1 / M2;
  const int c2  = tid % M2;
  const int lg  = tid / M2;

  // inverse twiddles (sign = +1)
  for (int i = tid; i < M2 / 2; i += 256) {
    float sv, cv;
    sincosf(6.28318530717958647692f / (float)M2 * (float)i, &sv, &cv);
    W[i] = make_float2(cv, sv);
  }

  float2 acc[LP][R];
  #pragma unroll
  for (int a = 0; a < LP; a++)
    #pragma unroll
    for (int r = 0; r < R; r++) acc[a][r] = make_float2(0.f, 0.f);

  const float2* sp = p.srcC + (long)s * m1 * m1;

  for (int r2loc = 0; r2loc < R; r2loc++) {
    const int r2 = rg * R + r2loc;
    __syncthreads();   // protect srow from previous iteration's readers
    for (int idx = tid; idx < k * m1; idx += 256) {
      const int qr = idx / m1, cc = idx - qr * m1;
      srow[qr][cc] = sp[(long)(r2 + qr * M2) * m1 + cc];
    }
    __syncthreads();
    for (int qr = 0; qr < k; qr++) {
      const int r = r2 + qr * M2;
      const float* fr = p.filt + (long)r * m1;
      for (int qc = 0; qc < k; qc++) {
        const int cc = c2 + qc * M2;
        const float2 sv = srow[qr][cc];
        #pragma unroll
        for (int lp = 0; lp < LP; lp++) {
          const float fv = fr[(long)(lg * LP + lp) * m1 * m1 + cc];
          acc[lp][r2loc].x = fmaf(sv.x, fv, acc[lp][r2loc].x);
          acc[lp][r2loc].y = fmaf(sv.y, fv, acc[lp][r2loc].y);
        }
      }
    }
  }

  // per l2: dump folded rows to LDS, inverse-FFT them, store transposed
  for (int l2 = 0; l2 < 8; l2++) {
    __syncthreads();
    if (lg == l2 / LP) {
      const int lp = l2 - (l2 / LP) * LP;
      #pragma unroll
      for (int r = 0; r < R; r++)
        Abuf[r][c2] = make_float2(acc[lp][r].x * p.scale, acc[lp][r].y * p.scale);
    }
    __syncthreads();
    #pragma unroll
    for (int t = 0; t < T; t++) {
      const int st = 1 << t;
      float2 (*Src)[M2 + 1] = (t & 1) ? Bbuf : Abuf;
      float2 (*Dst)[M2 + 1] = (t & 1) ? Abuf : Bbuf;
      for (int bf = tid; bf < R * (M2 / 2); bf += 256) {
        const int row = bf / (M2 / 2);
        const int j = bf - row * (M2 / 2);
        const float2 a = Src[row][j];
        const float2 b = Src[row][j + M2 / 2];
        const float2 w = W[j & ~(st - 1)];
        const float vx = a.x - b.x, vy = a.y - b.y;
        const int dc = (j & (st - 1)) + ((j >> t) << (t + 1));
        Dst[row][dc] = make_float2(a.x + b.x, a.y + b.y);
        Dst[row][dc + st] = make_float2(vx * w.x - vy * w.y, vx * w.y + vy * w.x);
      }
      __syncthreads();
    }
    float2 (*P)[M2 + 1] = (T & 1) ? Bbuf : Abuf;
    const long img = (long)s * 8 + l2;
    for (int idx = tid; idx < R * M2; idx += 256) {
      const int rl = idx & (R - 1);
      const int fo = idx / R;
      p.dstC[img * M2 * M2 + (long)fo * M2 + (rg * R + rl)] = P[rl][fo];
    }
  }
}

static void fold8_go(int M2, int nsrc, const Fold8Params& p, hipStream_t st) {
  const int blocks = nsrc * (M2 / 8);
  switch (M2) {
    case 128: fold8_kernel<128><<<blocks, 256, 0, st>>>(p); break;
    case  64: fold8_kernel< 64><<<blocks, 256, 0, st>>>(p); break;
    case  32: fold8_kernel< 32><<<blocks, 256, 0, st>>>(p); break;
  }
}

// ---------------------------------------------------------------------------
// Filter banks (computed on device in f64, mirroring numpy exactly)
// PSI banks: (r,js) = (0,0)(0,1)(0,2)(0,3)(1,1)(1,2)(2,1), 8 orientations each
// ---------------------------------------------------------------------------
__device__ const long PSI_CUM[7] = {524288, 1048576, 1572864, 2097152, 2228224, 2359296, 2392064};
__device__ const int  PSI_MM[7]  = {256, 256, 256, 256, 128, 128, 64};
__device__ const int  PSI_JS[7]  = {0, 1, 2, 3, 1, 2, 1};

__device__ __forceinline__ double dfreq(int i, int m) {
  return (double)((i < (m >> 1)) ? i : i - m) / (double)m;
}

// Grid is exactly 9344*256 = 2392064 threads; every 256-thread block lies
// entirely within one (bank, l) slice, so one atomicMax per BLOCK suffices.
__global__ __launch_bounds__(256) void build_psi_kernel(float* psi, int* fmax) {
  const long i = (long)blockIdx.x * 256 + threadIdx.x;
  int bank = 0;
  while (i >= PSI_CUM[bank]) bank++;
  const long base = bank ? PSI_CUM[bank - 1] : 0;
  const long rem = i - base;
  const int m = PSI_MM[bank], js = PSI_JS[bank];
  const long mm2 = (long)m * m;
  const int l = (int)(rem / mm2);
  const long pos = rem - (long)l * mm2;
  const int r = (int)(pos / m), c = (int)(pos - (long)r * m);
  const double sigma = 0.8 * (double)(1 << js);
  const double xi = (3.0 * PI_D / 4.0) / (double)(1 << js);
  const double th = (double)l * PI_D / 8.0;
  const double kx = 2.0 * PI_D * dfreq(r, m);
  const double ky = 2.0 * PI_D * dfreq(c, m);
  const double ct = cos(th), st = sin(th);
  const double w1 = kx * ct + ky * st;
  const double w2 = -kx * st + ky * ct;
  const double s2 = sigma * sigma;
  const double aa  = exp(-0.5 * s2 * ((w1 - xi) * (w1 - xi) + 0.25 * w2 * w2));
  const double env = exp(-0.5 * s2 * (w1 * w1 + 0.25 * w2 * w2));
  const double beta = exp(-0.5 * s2 * xi * xi);
  const double f = aa - beta * env;
  psi[i] = (float)f;

  float v = fmaxf((float)f, 0.f);
  #pragma unroll
  for (int off = 32; off > 0; off >>= 1)
    v = fmaxf(v, __shfl_down(v, off, 64));
  __shared__ float wmax[4];
  const int lane = threadIdx.x & 63, wid = threadIdx.x >> 6;
  if (lane == 0) wmax[wid] = v;
  __syncthreads();
  if (threadIdx.x == 0) {
    const float mv = fmaxf(fmaxf(wmax[0], wmax[1]), fmaxf(wmax[2], wmax[3]));
    atomicMax(&fmax[bank * 8 + l], __float_as_int(mv));
  }
}

__global__ void norm_psi_kernel(float* psi, const int* fmax) {
  const long i = (long)blockIdx.x * 256 + threadIdx.x;
  if (i >= 2392064L) return;
  int bank = 0;
  while (i >= PSI_CUM[bank]) bank++;
  const long base = bank ? PSI_CUM[bank - 1] : 0;
  const long rem = i - base;
  const int m = PSI_MM[bank];
  const int l = (int)(rem / ((long)m * m));
  const float mx = fmaxf(__int_as_float(fmax[bank * 8 + l]), 1e-12f);
  psi[i] = psi[i] / mx;
}

__global__ void build_phi_kernel(float* phi) {
  const long i = (long)blockIdx.x * 256 + threadIdx.x;
  if (i >= 87040L) return;
  int rr; long base;
  if (i < 65536) { rr = 0; base = 0; }
  else if (i < 81920) { rr = 1; base = 65536; }
  else if (i < 86016) { rr = 2; base = 81920; }
  else { rr = 3; base = 86016; }
  const int m = 256 >> rr;
  const double sigma = 0.8 * (double)(1 << (4 - rr));
  const long pos = i - base;
  const int r = (int)(pos / m), c = (int)(pos % m);
  const double kx = 2.0 * PI_D * dfreq(r, m);
  const double ky = 2.0 * PI_D * dfreq(c, m);
  phi[i] = (float)exp(-0.5 * sigma * sigma * (kx * kx + ky * ky));
}

// ---------------------------------------------------------------------------
// MLP
// ---------------------------------------------------------------------------
__global__ __launch_bounds__(256) void mlp1_kernel(const float* __restrict__ S,
                                                   const float* __restrict__ w1,
                                                   float* __restrict__ out1) {
  __shared__ float hs[16][256];
  const int o = blockIdx.x * 256 + threadIdx.x;   // 1024 outputs over 4 blocks
  const int ch = blockIdx.y;                      // 417 k-chunks of 256
  for (int idx = threadIdx.x; idx < 16 * 256; idx += 256) {
    const int b = idx >> 8, kk = idx & 255;
    hs[b][kk] = S[((long)b * 417 + ch) * 256 + kk];
  }
  __syncthreads();
  float acc[16];
  #pragma unroll
  for (int b = 0; b < 16; b++) acc[b] = 0.f;
  const float* wp = w1 + (long)ch * 256 * 1024 + o;
  for (int kk = 0; kk < 256; kk++) {
    const float w = wp[(long)kk * 1024];
    #pragma unroll
    for (int b = 0; b < 16; b++) acc[b] = fmaf(hs[b][kk], w, acc[b]);
  }
  #pragma unroll
  for (int b = 0; b < 16; b++) atomicAdd(&out1[b * 1024 + o], acc[b]);
}

__global__ void l1post_kernel(const float* out1, const float* b1, const float* g,
                              const float* bb, const float* mm, const float* vv, float* h1) {
  const int i = blockIdx.x * 256 + threadIdx.x;
  if (i < 16384) {
    const int o = i & 1023;
    const float xv = fmaxf(out1[i] + b1[o], 0.f);
    const float rs = (float)(1.0 / sqrt((double)vv[o] + 1e-5));
    h1[i] = (xv - mm[o]) * rs * g[o] + bb[o];
  }
}

__global__ __launch_bounds__(256) void mlp2_kernel(const float* h1, const float* w2, const float* b2,
                                                   const float* g, const float* bb, const float* mm,
                                                   const float* vv, float* h2) {
  __shared__ float hs[16][256];
  const int o = blockIdx.x * 256 + threadIdx.x;   // 512 outputs over 2 blocks
  float acc[16];
  #pragma unroll
  for (int b = 0; b < 16; b++) acc[b] = 0.f;
  for (int kc = 0; kc < 4; kc++) {
    __syncthreads();
    for (int idx = threadIdx.x; idx < 16 * 256; idx += 256) {
      const int b = idx >> 8, kk = idx & 255;
      hs[b][kk] = h1[b * 1024 + kc * 256 + kk];
    }
    __syncthreads();
    for (int kk = 0; kk < 256; kk++) {
      const float w = w2[(long)(kc * 256 + kk) * 512 + o];
      #pragma unroll
      for (int b = 0; b < 16; b++) acc[b] = fmaf(hs[b][kk], w, acc[b]);
    }
  }
  const float bias = b2[o], gg = g[o], bbv = bb[o], mv = mm[o];
  const float rs = (float)(1.0 / sqrt((double)vv[o] + 1e-5));
  for (int b = 0; b < 16; b++) {
    const float xv = fmaxf(acc[b] + bias, 0.f);
    h2[b * 512 + o] = (xv - mv) * rs * gg + bbv;
  }
}

__global__ __launch_bounds__(128) void mlp3_kernel(const float* h2, const float* w3, const float* b3,
                                                   const float* g, const float* bb, const float* mm,
                                                   const float* vv, float* h3) {
  __shared__ float hs[16][256];
  const int o = threadIdx.x;   // 128 outputs
  float acc[16];
  #pragma unroll
  for (int b = 0; b < 16; b++) acc[b] = 0.f;
  for (int kc = 0; kc < 2; kc++) {
    __syncthreads();
    for (int idx = threadIdx.x; idx < 16 * 256; idx += 128) {
      const int b = idx >> 8, kk = idx & 255;
      hs[b][kk] = h2[b * 512 + kc * 256 + kk];
    }
    __syncthreads();
    for (int kk = 0; kk < 256; kk++) {
      const float w = w3[(kc * 256 + kk) * 128 + o];
      #pragma unroll
      for (int b = 0; b < 16; b++) acc[b] = fmaf(hs[b][kk], w, acc[b]);
    }
  }
  const float bias = b3[o], gg = g[o], bbv = bb[o], mv = mm[o];
  const float rs = (float)(1.0 / sqrt((double)vv[o] + 1e-5));
  for (int b = 0; b < 16; b++) {
    const float xv = fmaxf(acc[b] + bias, 0.f);
    h3[b * 128 + o] = (xv - mv) * rs * gg + bbv;
  }
}

__global__ void mlp4_kernel(const float* h3, const float* w4, const float* b4, float* out) {
  const int b = threadIdx.x;
  if (b < 16) {
    double a = 0.0;
    for (int k = 0; k < 128; k++) a += (double)h3[b * 128 + k] * (double)w4[k];
    out[b] = (float)(a + (double)b4[0]);
  }
}

// ---------------------------------------------------------------------------
// Orchestration
// ---------------------------------------------------------------------------
static RftParams rp0() {
  RftParams p;
  memset(&p, 0, sizeof(p));
  p.srcDiv = 1; p.filtMod = 1; p.chDiv = 1;
  p.scale = 1.f; p.sign = -1.f; p.m1 = 0;
  return p;
}

extern "C" void kernel_launch(void* const* d_in, const int* in_sizes, int n_in,
                              void* d_out, int out_size, void* d_ws, size_t ws_size,
                              hipStream_t stream) {
  (void)in_sizes; (void)n_in; (void)out_size; (void)ws_size;
  const float* x    = (const float*)d_in[0];
  const float* w1   = (const float*)d_in[1];
  const float* b1   = (const float*)d_in[2];
  const float* bn1g = (const float*)d_in[3];
  const float* bn1b = (const float*)d_in[4];
  const float* bn1m = (const float*)d_in[5];
  const float* bn1v = (const float*)d_in[6];
  const float* w2   = (const float*)d_in[7];
  const float* b2   = (const float*)d_in[8];
  const float* bn2g = (const float*)d_in[9];
  const float* bn2b = (const float*)d_in[10];
  const float* bn2m = (const float*)d_in[11];
  const float* bn2v = (const float*)d_in[12];
  const float* w3   = (const float*)d_in[13];
  const float* b3   = (const float*)d_in[14];
  const float* bn3g = (const float*)d_in[15];
  const float* bn3b = (const float*)d_in[16];
  const float* bn3m = (const float*)d_in[17];
  const float* bn3v = (const float*)d_in[18];
  const float* w4   = (const float*)d_in[19];
  const float* b4   = (const float*)d_in[20];

  char* ws = (char*)d_ws;
  // ws_size observed ~1.75 GB (R2 fill counter: 1.708e6 KB) -- use ~420 MB.
  const long MB = 1024L * 1024L;
  float2* XF   = (float2*)(ws);                //   8 MB: fft2(x), 16 x 256^2
  float2* U1F  = (float2*)(ws + 8 * MB);       //  64 MB: fft2(u1), up to 128 x 256^2
  float2* BUF1 = (float2*)(ws + 80 * MB);      // 160 MB ping
  float2* BUF2 = (float2*)(ws + 240 * MB);     // 160 MB pong
  float*  S    = (float*)(ws + 400 * MB);      // 16 x 417 x 256
  float*  PSI  = (float*)(ws + 408 * MB);      // 2392064 floats
  float*  PHI  = (float*)(ws + 418 * MB);      // 87040 floats
  int*    FMAX = (int*)(ws + 419 * MB);        // 56 slots
  float*  OUT1 = (float*)(ws + 419 * MB + 4096);
  float*  H1   = (float*)(ws + 419 * MB + 4096 + 65536);
  float*  H2   = (float*)(ws + 419 * MB + 4096 + 131072);
  float*  H3   = (float*)(ws + 419 * MB + 4096 + 196608);

  static const int psioff[7] = {0, 524288, 1048576, 1572864, 2097152, 2228224, 2359296};
  static const int phioff[4] = {0, 65536, 81920, 86016};

  // ---- filters (deterministic, rebuilt every call) ----
  hipMemsetAsync(FMAX, 0, 256, stream);
  build_psi_kernel<<<9344, 256, 0, stream>>>(PSI, FMAX);
  norm_psi_kernel<<<9344, 256, 0, stream>>>(PSI, FMAX);
  build_phi_kernel<<<340, 256, 0, stream>>>(PHI);

  // ---- Xf = fft2(x) ----
  { RftParams p = rp0(); p.inMode = IN_REAL; p.srcR = x; p.outMode = OUT_COMPLEX; p.dstC = BUF1; p.sign = -1.f; rft_go(256, 16, p, stream); }
  { RftParams p = rp0(); p.inMode = IN_COMPLEX; p.srcC = BUF1; p.outMode = OUT_COMPLEX; p.dstC = XF; p.sign = -1.f; rft_go(256, 16, p, stream); }

  // ---- s0 = Re(ifft16(fold(Xf*phi0))) ----
  { RftParams p = rp0(); p.inMode = IN_MULFOLD; p.srcC = XF; p.filt = PHI + phioff[0]; p.m1 = 256; p.srcDiv = 1; p.filtMod = 1; p.scale = 1.f / 65536.f; p.sign = 1.f; p.outMode = OUT_COMPLEX; p.dstC = BUF1; rft_go(16, 16, p, stream); }
  { RftParams p = rp0(); p.inMode = IN_COMPLEX; p.srcC = BUF1; p.sign = 1.f; p.outMode = OUT_REAL_S; p.dstR = S; p.chDiv = 1; p.chBase = 0; p.b0 = 0; rft_go(16, 16, p, stream); }

  for (int j1 = 0; j1 < 4; j1++) {
    const int m1 = 256 >> j1;
    const float isc1 = 1.f / (float)(m1 * m1);
    // u1 pass-1: fold Xf through the 8 psi_(0,j1) filters + ifft pass 1
    if (j1 == 0) {
      // k=1 (no fold): plain per-image multiply path
      RftParams p = rp0(); p.inMode = IN_MULFOLD; p.srcC = XF; p.filt = PSI + psioff[0]; p.m1 = 256; p.srcDiv = 8; p.filtMod = 8; p.scale = 1.f / 65536.f; p.sign = 1.f; p.outMode = OUT_COMPLEX; p.dstC = BUF1; rft_go(256, 128, p, stream);
    } else {
      Fold8Params f; f.srcC = XF; f.filt = PSI + psioff[j1]; f.dstC = BUF1; f.m1 = 256; f.scale = 1.f / 65536.f;
      fold8_go(m1, 16, f, stream);
    }
    // ifft pass 2 + abs -> u1 (real) in BUF2
    { RftParams p = rp0(); p.inMode = IN_COMPLEX; p.srcC = BUF1; p.sign = 1.f; p.outMode = OUT_ABS; p.dstR = (float*)BUF2; rft_go(m1, 128, p, stream); }
    // u1f = fft2(u1)
    { RftParams p = rp0(); p.inMode = IN_REAL; p.srcR = (const float*)BUF2; p.sign = -1.f; p.outMode = OUT_COMPLEX; p.dstC = BUF1; rft_go(m1, 128, p, stream); }
    { RftParams p = rp0(); p.inMode = IN_COMPLEX; p.srcC = BUF1; p.sign = -1.f; p.outMode = OUT_COMPLEX; p.dstC = U1F; rft_go(m1, 128, p, stream); }
    // s1 = Re(ifft16(fold(u1f * phi_j1)))
    { RftParams p = rp0(); p.inMode = IN_MULFOLD; p.srcC = U1F; p.filt = PHI + phioff[j1]; p.m1 = m1; p.srcDiv = 1; p.filtMod = 1; p.scale = isc1; p.sign = 1.f; p.outMode = OUT_COMPLEX; p.dstC = BUF1; rft_go(16, 128, p, stream); }
    { RftParams p = rp0(); p.inMode = IN_COMPLEX; p.srcC = BUF1; p.sign = 1.f; p.outMode = OUT_REAL_S; p.dstR = S; p.chDiv = 8; p.chBase = 1 + 8 * j1; p.b0 = 0; rft_go(16, 128, p, stream); }

    for (int j2 = j1 + 1; j2 < 4; j2++) {
      const int m2 = 256 >> j2;
      const float isc2 = 1.f / (float)(m2 * m2);
      int bank;
      if (j1 == 0) bank = j2;            // PSI[(0,j2)]
      else if (j1 == 1) bank = j2 + 2;   // PSI[(1,1)]->4, PSI[(1,2)]->5
      else bank = 6;                     // PSI[(2,1)]
      const int pairIdx = (j1 == 0) ? (j2 - 1) : ((j1 == 1) ? (j2 + 1) : 5);
      const int chb = 33 + 64 * pairIdx;
      const int nimg = 1024;             // (b,l1,l2) in one batch
      // u2 pass-1: fold u1f through 8 psi_(j1,j2-j1) filters + ifft pass 1
      { Fold8Params f; f.srcC = U1F; f.filt = PSI + psioff[bank]; f.dstC = BUF1; f.m1 = m1; f.scale = isc1; fold8_go(m2, 128, f, stream); }
      // ifft pass 2 + abs -> u2 (real) in BUF2
      { RftParams p = rp0(); p.inMode = IN_COMPLEX; p.srcC = BUF1; p.sign = 1.f; p.outMode = OUT_ABS; p.dstR = (float*)BUF2; rft_go(m2, nimg, p, stream); }
      // u2f = fft2(u2)
      { RftParams p = rp0(); p.inMode = IN_REAL; p.srcR = (const float*)BUF2; p.sign = -1.f; p.outMode = OUT_COMPLEX; p.dstC = BUF1; rft_go(m2, nimg, p, stream); }
      { RftParams p = rp0(); p.inMode = IN_COMPLEX; p.srcC = BUF1; p.sign = -1.f; p.outMode = OUT_COMPLEX; p.dstC = BUF2; rft_go(m2, nimg, p, stream); }
      // s2 = Re(ifft16(fold(u2f * phi_j2)))
      { RftParams p = rp0(); p.inMode = IN_MULFOLD; p.srcC = BUF2; p.filt = PHI + phioff[j2]; p.m1 = m2; p.srcDiv = 1; p.filtMod = 1; p.scale = isc2; p.sign = 1.f; p.outMode = OUT_COMPLEX; p.dstC = BUF1; rft_go(16, nimg, p, stream); }
      { RftParams p = rp0(); p.inMode = IN_COMPLEX; p.srcC = BUF1; p.sign = 1.f; p.outMode = OUT_REAL_S; p.dstR = S; p.chDiv = 64; p.chBase = chb; p.b0 = 0; rft_go(16, nimg, p, stream); }
    }
  }

  // ---- MLP ----
  hipMemsetAsync(OUT1, 0, 16 * 1024 * 4, stream);
  mlp1_kernel<<<dim3(4, 417), 256, 0, stream>>>(S, w1, OUT1);
  l1post_kernel<<<64, 256, 0, stream>>>(OUT1, b1, bn1g, bn1b, bn1m, bn1v, H1);
  mlp2_kernel<<<2, 256, 0, stream>>>(H1, w2, b2, bn2g, bn2b, bn2m, bn2v, H2);
  mlp3_kernel<<<1, 128, 0, stream>>>(H2, w3, b3, bn3g, bn3b, bn3m, bn3v, H3);
  mlp4_kernel<<<1, 64, 0, stream>>>(H3, w4, b4, (float*)d_out);
}

// Round 4
// 2502.762 us; speedup vs baseline: 1.0345x; 1.0345x over previous
//
#include <hip/hip_runtime.h>
#include <math.h>
#include <string.h>

#define PI_D 3.14159265358979323846264338327950288

// ---------------------------------------------------------------------------
// Scattering2D (J=4, L=8, 256x256, B=16) + MLP, all fp32.
// 2D FFT = row-Stockham-FFT-with-transposed-write applied twice.
// Subsampling = spectrum folding fused into pass-1 load.
// R4: fused whole-image tail kernels for M<=64 (chain of 6 kernels -> 1-2);
//     fold8 kept only at u2 sites (nsrc=128); u1 j1=0,1 revert to R2 chains
//     (R3 regression: fold8 u1 grids of 64-256 blocks underfilled the GPU);
//     filter build f64 -> f32.
// ---------------------------------------------------------------------------

enum { IN_COMPLEX = 0, IN_REAL = 1, IN_MULFOLD = 2 };
enum { OUT_COMPLEX = 0, OUT_ABS = 1, OUT_REAL_S = 2 };

struct RftParams {
  const float2* srcC;
  const float*  srcR;
  const float*  filt;
  float2* dstC;
  float*  dstR;
  int m1;        // source resolution for MULFOLD
  int srcDiv;    // source image = img / srcDiv
  int filtMod;   // filter index = img % filtMod
  float scale;   // ifft scale (1/m1^2), applied at load
  float sign;    // -1 forward, +1 inverse
  int chDiv, chBase, b0;   // S-write addressing
  int inMode, outMode;
};

template<int M>
__global__ __launch_bounds__(256) void rft_kernel(RftParams p) {
  constexpr int R = (M >= 64) ? 8 : ((M == 32) ? 16 : 32);   // rows per block
  constexpr int T = (M == 16) ? 4 : ((M == 32) ? 5 : ((M == 64) ? 6 : ((M == 128) ? 7 : 8)));
  __shared__ float2 Abuf[R][M + 1];
  __shared__ float2 Bbuf[R][M + 1];
  __shared__ float2 W[M / 2];
  const int tid = threadIdx.x;
  const long rows0 = (long)blockIdx.x * R;

  {
    const float base = p.sign * 6.28318530717958647692f / (float)M;
    for (int i = tid; i < M / 2; i += 256) {
      float sv, cv;
      sincosf(base * (float)i, &sv, &cv);
      W[i] = make_float2(cv, sv);
    }
  }

  if (p.inMode == IN_COMPLEX) {
    const float2* s = p.srcC + rows0 * M;
    for (int idx = tid; idx < R * M; idx += 256)
      Abuf[idx / M][idx % M] = s[idx];
  } else if (p.inMode == IN_REAL) {
    const float* s = p.srcR + rows0 * M;
    for (int idx = tid; idx < R * M; idx += 256)
      Abuf[idx / M][idx % M] = make_float2(s[idx], 0.f);
  } else {  // IN_MULFOLD
    const int m1 = p.m1;
    const int k = m1 / M;
    for (int idx = tid; idx < R * M; idx += 256) {
      const int rl = idx / M, c = idx % M;
      const long g = rows0 + rl;
      const long img = g / M;
      const int r = (int)(g - img * M);
      const float2* sp = p.srcC + (img / p.srcDiv) * (long)m1 * m1;
      const float* fp = p.filt + (long)(img % p.filtMod) * m1 * m1;
      float re = 0.f, im = 0.f;
      for (int qr = 0; qr < k; qr++) {
        const long ro = (long)(r + qr * M) * m1;
        const float2* srow = sp + ro;
        const float*  frow = fp + ro;
        for (int qc = 0; qc < k; qc++) {
          const int cc = c + qc * M;
          const float2 v = srow[cc];
          const float fv = frow[cc];
          re = fmaf(v.x, fv, re);
          im = fmaf(v.y, fv, im);
        }
      }
      Abuf[rl][c] = make_float2(re * p.scale, im * p.scale);
    }
  }
  __syncthreads();

  #pragma unroll
  for (int t = 0; t < T; t++) {
    const int s = 1 << t;
    float2 (*Src)[M + 1] = (t & 1) ? Bbuf : Abuf;
    float2 (*Dst)[M + 1] = (t & 1) ? Abuf : Bbuf;
    for (int bf = tid; bf < R * (M / 2); bf += 256) {
      const int row = bf / (M / 2);
      const int j = bf - row * (M / 2);
      const float2 a = Src[row][j];
      const float2 b = Src[row][j + M / 2];
      const float2 w = W[j & ~(s - 1)];
      const float vx = a.x - b.x, vy = a.y - b.y;
      const int dc = (j & (s - 1)) + ((j >> t) << (t + 1));
      Dst[row][dc] = make_float2(a.x + b.x, a.y + b.y);
      Dst[row][dc + s] = make_float2(vx * w.x - vy * w.y, vx * w.y + vy * w.x);
    }
    __syncthreads();
  }
  float2 (*P)[M + 1] = (T & 1) ? Bbuf : Abuf;

  if (p.outMode == OUT_COMPLEX) {
    for (int idx = tid; idx < R * M; idx += 256) {
      const int rl = idx & (R - 1);
      const int fo = idx / R;
      const long g = rows0 + rl;
      const long img = g / M;
      const int rpos = (int)(g - img * M);
      p.dstC[img * (long)M * M + (long)fo * M + rpos] = P[rl][fo];
    }
  } else if (p.outMode == OUT_ABS) {
    for (int idx = tid; idx < R * M; idx += 256) {
      const int rl = idx & (R - 1);
      const int fo = idx / R;
      const long g = rows0 + rl;
      const long img = g / M;
      const int rpos = (int)(g - img * M);
      const float2 z = P[rl][fo];
      p.dstR[img * (long)M * M + (long)fo * M + rpos] = sqrtf(z.x * z.x + z.y * z.y);
    }
  } else {  // OUT_REAL_S (M == 16)
    for (int idx = tid; idx < R * M; idx += 256) {
      const int rl = idx & (R - 1);
      const int fo = idx / R;
      const long g = rows0 + rl;
      const long img = g / M;
      const int rpos = (int)(g - img * M);
      const int bidx = (int)(img / p.chDiv) + p.b0;
      const int ch = p.chBase + (int)(img % p.chDiv);
      p.dstR[((long)bidx * 417 + ch) * 256 + fo * M + rpos] = P[rl][fo].x;
    }
  }
}

static void rft_go(int M, int nimg, const RftParams& p, hipStream_t st) {
  const int R = (M >= 64) ? 8 : ((M == 32) ? 16 : 32);
  const int blocks = nimg * M / R;
  switch (M) {
    case 256: rft_kernel<256><<<blocks, 256, 0, st>>>(p); break;
    case 128: rft_kernel<128><<<blocks, 256, 0, st>>>(p); break;
    case  64: rft_kernel< 64><<<blocks, 256, 0, st>>>(p); break;
    case  32: rft_kernel< 32><<<blocks, 256, 0, st>>>(p); break;
    case  16: rft_kernel< 16><<<blocks, 256, 0, st>>>(p); break;
  }
}

// ---------------------------------------------------------------------------
// fold8: per source spectrum, fold through ALL 8 filters of a psi bank and
// run ifft pass-1, in one kernel. Source rows read once. Used only at u2
// sites (nsrc=128 -> 512..2048 blocks).
// ---------------------------------------------------------------------------
struct Fold8Params {
  const float2* srcC;
  const float*  filt;
  float2* dstC;
  int m1;
  float scale;
};

template<int M2>
__global__ __launch_bounds__(256) void fold8_kernel(Fold8Params p) {
  constexpr int R = 8;
  constexpr int T = (M2 == 32) ? 5 : ((M2 == 64) ? 6 : 7);
  constexpr int G = 256 / M2;
  constexpr int LP = 8 / G;
  __shared__ float2 srow[8][256];
  __shared__ float2 Abuf[R][M2 + 1];
  __shared__ float2 Bbuf[R][M2 + 1];
  __shared__ float2 W[M2 / 2];
  const int tid = threadIdx.x;
  const int nrg = M2 / R;
  const int s   = blockIdx.x / nrg;
  const int rg  = blockIdx.x % nrg;
  const int m1  = p.m1;
  const int k   = m1 / M2;
  const int c2  = tid % M2;
  const int lg  = tid / M2;

  for (int i = tid; i < M2 / 2; i += 256) {
    float sv, cv;
    sincosf(6.28318530717958647692f / (float)M2 * (float)i, &sv, &cv);
    W[i] = make_float2(cv, sv);
  }

  float2 acc[LP][R];
  #pragma unroll
  for (int a = 0; a < LP; a++)
    #pragma unroll
    for (int r = 0; r < R; r++) acc[a][r] = make_float2(0.f, 0.f);

  const float2* sp = p.srcC + (long)s * m1 * m1;

  for (int r2loc = 0; r2loc < R; r2loc++) {
    const int r2 = rg * R + r2loc;
    __syncthreads();
    for (int idx = tid; idx < k * m1; idx += 256) {
      const int qr = idx / m1, cc = idx - qr * m1;
      srow[qr][cc] = sp[(long)(r2 + qr * M2) * m1 + cc];
    }
    __syncthreads();
    for (int qr = 0; qr < k; qr++) {
      const int r = r2 + qr * M2;
      const float* fr = p.filt + (long)r * m1;
      for (int qc = 0; qc < k; qc++) {
        const int cc = c2 + qc * M2;
        const float2 sv = srow[qr][cc];
        #pragma unroll
        for (int lp = 0; lp < LP; lp++) {
          const float fv = fr[(long)(lg * LP + lp) * m1 * m1 + cc];
          acc[lp][r2loc].x = fmaf(sv.x, fv, acc[lp][r2loc].x);
          acc[lp][r2loc].y = fmaf(sv.y, fv, acc[lp][r2loc].y);
        }
      }
    }
  }

  for (int l2 = 0; l2 < 8; l2++) {
    __syncthreads();
    if (lg == l2 / LP) {
      const int lp = l2 - (l2 / LP) * LP;
      #pragma unroll
      for (int r = 0; r < R; r++)
        Abuf[r][c2] = make_float2(acc[lp][r].x * p.scale, acc[lp][r].y * p.scale);
    }
    __syncthreads();
    #pragma unroll
    for (int t = 0; t < T; t++) {
      const int st = 1 << t;
      float2 (*Src)[M2 + 1] = (t & 1) ? Bbuf : Abuf;
      float2 (*Dst)[M2 + 1] = (t & 1) ? Abuf : Bbuf;
      for (int bf = tid; bf < R * (M2 / 2); bf += 256) {
        const int row = bf / (M2 / 2);
        const int j = bf - row * (M2 / 2);
        const float2 a = Src[row][j];
        const float2 b = Src[row][j + M2 / 2];
        const float2 w = W[j & ~(st - 1)];
        const float vx = a.x - b.x, vy = a.y - b.y;
        const int dc = (j & (st - 1)) + ((j >> t) << (t + 1));
        Dst[row][dc] = make_float2(a.x + b.x, a.y + b.y);
        Dst[row][dc + st] = make_float2(vx * w.x - vy * w.y, vx * w.y + vy * w.x);
      }
      __syncthreads();
    }
    float2 (*P)[M2 + 1] = (T & 1) ? Bbuf : Abuf;
    const long img = (long)s * 8 + l2;
    for (int idx = tid; idx < R * M2; idx += 256) {
      const int rl = idx & (R - 1);
      const int fo = idx / R;
      p.dstC[img * M2 * M2 + (long)fo * M2 + (rg * R + rl)] = P[rl][fo];
    }
  }
}

static void fold8_go(int M2, int nsrc, const Fold8Params& p, hipStream_t st) {
  const int blocks = nsrc * (M2 / 8);
  switch (M2) {
    case 128: fold8_kernel<128><<<blocks, 256, 0, st>>>(p); break;
    case  64: fold8_kernel< 64><<<blocks, 256, 0, st>>>(p); break;
    case  32: fold8_kernel< 32><<<blocks, 256, 0, st>>>(p); break;
  }
}

// ---------------------------------------------------------------------------
// Fused whole-image tail (M <= 64): [optional fold-from-XF + pass1] +
// pass2+abs + fft2 (pass3, pass4) + optional U1F write + phi-fold + ifft16
// + S write. Semantics identical to the rft chain: every pass is
// "FFT rows, store transposed" with the same fold order and scales.
// ---------------------------------------------------------------------------
struct TailParams {
  const float2* srcP1;   // mode 0: pass-1 spectrum (fold8 output)
  const float2* foldSrc; // mode 1: XF (256^2 spectra)
  const float*  foldFilt;// mode 1: psi bank base (8 filters at 256^2)
  const float*  phi;     // phi_j at M^2
  float2* u1fOut;        // nullable: write u1f spectra (M^2 each)
  float*  S;
  float foldScale, sfScale;
  int chDiv, chBase;
  int mode;
};

template<int M, int T>
__device__ __forceinline__ void stockham_stages(float2 (*&x)[M + 1], float2 (*&y)[M + 1],
                                                const float2* W, int tid) {
  #pragma unroll
  for (int t = 0; t < T; t++) {
    const int s = 1 << t;
    for (int bf = tid; bf < M * (M / 2); bf += 256) {
      const int row = bf / (M / 2);
      const int j = bf - row * (M / 2);
      const float2 a = x[row][j];
      const float2 b = x[row][j + M / 2];
      const float2 w = W[j & ~(s - 1)];
      const float vx = a.x - b.x, vy = a.y - b.y;
      const int dc = (j & (s - 1)) + ((j >> t) << (t + 1));
      y[row][dc] = make_float2(a.x + b.x, a.y + b.y);
      y[row][dc + s] = make_float2(vx * w.x - vy * w.y, vx * w.y + vy * w.x);
    }
    __syncthreads();
    float2 (*tmp)[M + 1] = x; x = y; y = tmp;
  }
}

// One rft-equivalent pass: cur := transpose(FFT_rows(cur)) (optionally |.|).
template<int M, int T>
__device__ __forceinline__ void fft_pass_t(float2 (*&cur)[M + 1], float2 (*A)[M + 1],
                                           float2 (*B)[M + 1], const float2* W,
                                           bool doAbs, int tid) {
  float2 (*x)[M + 1] = cur;
  float2 (*y)[M + 1] = (cur == A) ? B : A;
  stockham_stages<M, T>(x, y, W, tid);
  for (int idx = tid; idx < M * M; idx += 256) {
    const int r = idx / M, c = idx - r * M;
    const float2 v = x[r][c];
    y[c][r] = doAbs ? make_float2(sqrtf(v.x * v.x + v.y * v.y), 0.f) : v;
  }
  __syncthreads();
  cur = y;
}

__device__ __forceinline__ void fft16_pass(float2 (*&cur)[17], float2 (*Ha)[17],
                                           float2 (*Hb)[17], const float2* Wp,
                                           int wstride, int tid) {
  float2 (*x)[17] = cur;
  float2 (*y)[17] = (cur == Ha) ? Hb : Ha;
  #pragma unroll
  for (int t = 0; t < 4; t++) {
    const int s = 1 << t;
    if (tid < 128) {
      const int row = tid / 8;
      const int j = tid & 7;
      const float2 a = x[row][j];
      const float2 b = x[row][j + 8];
      const float2 w = Wp[(j & ~(s - 1)) * wstride];
      const float vx = a.x - b.x, vy = a.y - b.y;
      const int dc = (j & (s - 1)) + ((j >> t) << (t + 1));
      y[row][dc] = make_float2(a.x + b.x, a.y + b.y);
      y[row][dc + s] = make_float2(vx * w.x - vy * w.y, vx * w.y + vy * w.x);
    }
    __syncthreads();
    float2 (*tmp)[17] = x; x = y; y = tmp;
  }
  {
    const int r = tid / 16, c = tid & 15;
    y[c][r] = x[r][c];
  }
  __syncthreads();
  cur = y;
}

template<int M>
__global__ __launch_bounds__(256) void tail_kernel(TailParams p) {
  constexpr int T = (M == 32) ? 5 : 6;
  __shared__ float2 A[M][M + 1];
  __shared__ float2 B[M][M + 1];
  __shared__ float2 Ha[16][17];
  __shared__ float2 Hb[16][17];
  __shared__ float2 Wp[M / 2];
  __shared__ float2 Wm[M / 2];
  const int tid = threadIdx.x;
  const int img = blockIdx.x;

  for (int i = tid; i < M / 2; i += 256) {
    float sv, cv;
    sincosf(6.28318530717958647692f / (float)M * (float)i, &sv, &cv);
    Wp[i] = make_float2(cv, sv);
    Wm[i] = make_float2(cv, -sv);
  }

  if (p.mode == 0) {
    const float2* s = p.srcP1 + (long)img * M * M;
    for (int idx = tid; idx < M * M; idx += 256)
      A[idx / M][idx % M] = s[idx];
  } else {
    const int k = 256 / M;
    const float2* sp = p.foldSrc + (long)(img >> 3) * 65536;
    const float*  fp = p.foldFilt + (long)(img & 7) * 65536;
    for (int idx = tid; idx < M * M; idx += 256) {
      const int r = idx / M, c = idx - (idx / M) * M;
      float re = 0.f, im = 0.f;
      for (int qr = 0; qr < k; qr++) {
        const int base = (r + qr * M) * 256;
        for (int qc = 0; qc < k; qc++) {
          const int cc = base + c + qc * M;
          const float2 v = sp[cc];
          const float fv = fp[cc];
          re = fmaf(v.x, fv, re);
          im = fmaf(v.y, fv, im);
        }
      }
      A[r][c] = make_float2(re * p.foldScale, im * p.foldScale);
    }
  }
  __syncthreads();

  float2 (*cur)[M + 1] = A;
  if (p.mode == 1) fft_pass_t<M, T>(cur, A, B, Wp, false, tid);  // pass1 (ifft rows)
  fft_pass_t<M, T>(cur, A, B, Wp, true,  tid);                   // pass2 + abs -> u
  fft_pass_t<M, T>(cur, A, B, Wm, false, tid);                   // fft pass1
  fft_pass_t<M, T>(cur, A, B, Wm, false, tid);                   // fft pass2 -> uf (standard layout)

  if (p.u1fOut) {
    float2* d = p.u1fOut + (long)img * M * M;
    for (int idx = tid; idx < M * M; idx += 256)
      d[idx] = cur[idx / M][idx % M];
    __syncthreads();
  }

  // phi-fold M^2 -> 16^2 (qr outer, qc inner, same order as rft MULFOLD)
  {
    const int k16 = M / 16;
    const int r = tid / 16, c = tid & 15;
    float re = 0.f, im = 0.f;
    for (int qr = 0; qr < k16; qr++) {
      const int rr = r + 16 * qr;
      for (int qc = 0; qc < k16; qc++) {
        const int cc = c + 16 * qc;
        const float2 v = cur[rr][cc];
        const float fv = p.phi[rr * M + cc];
        re = fmaf(v.x, fv, re);
        im = fmaf(v.y, fv, im);
      }
    }
    Ha[r][c] = make_float2(re * p.sfScale, im * p.sfScale);
  }
  __syncthreads();

  float2 (*cur16)[17] = Ha;
  fft16_pass(cur16, Ha, Hb, Wp, M / 16, tid);
  fft16_pass(cur16, Ha, Hb, Wp, M / 16, tid);

  const int bidx = img / p.chDiv;
  const int ch = p.chBase + (img % p.chDiv);
  p.S[((long)bidx * 417 + ch) * 256 + tid] = cur16[tid / 16][tid & 15].x;
}

// ---------------------------------------------------------------------------
// Filter banks (f32 on device; threshold 4.4e-4 >> f32 drift ~1e-6)
// PSI banks: (r,js) = (0,0)(0,1)(0,2)(0,3)(1,1)(1,2)(2,1), 8 orientations each
// ---------------------------------------------------------------------------
__device__ const long PSI_CUM[7] = {524288, 1048576, 1572864, 2097152, 2228224, 2359296, 2392064};
__device__ const int  PSI_MM[7]  = {256, 256, 256, 256, 128, 128, 64};
__device__ const int  PSI_JS[7]  = {0, 1, 2, 3, 1, 2, 1};

__device__ __forceinline__ float dfreq_f(int i, int m) {
  return (float)((i < (m >> 1)) ? i : i - m) / (float)m;
}

// Every 256-thread block lies in one (bank,l) slice -> one atomicMax/block.
__global__ __launch_bounds__(256) void build_psi_kernel(float* psi, int* fmax) {
  const long i = (long)blockIdx.x * 256 + threadIdx.x;
  int bank = 0;
  while (i >= PSI_CUM[bank]) bank++;
  const long base = bank ? PSI_CUM[bank - 1] : 0;
  const long rem = i - base;
  const int m = PSI_MM[bank], js = PSI_JS[bank];
  const long mm2 = (long)m * m;
  const int l = (int)(rem / mm2);
  const long pos = rem - (long)l * mm2;
  const int r = (int)(pos / m), c = (int)(pos - (long)r * m);
  const float sigma = 0.8f * (float)(1 << js);
  const float xi = 2.35619449019234492885f / (float)(1 << js);   // 3*pi/4
  float ths, thc;
  sincosf((float)l * 0.39269908169872415481f, &ths, &thc);        // pi/8
  const float kx = 6.28318530717958647692f * dfreq_f(r, m);
  const float ky = 6.28318530717958647692f * dfreq_f(c, m);
  const float w1 = kx * thc + ky * ths;
  const float w2 = -kx * ths + ky * thc;
  const float s2 = sigma * sigma;
  const float aa  = expf(-0.5f * s2 * ((w1 - xi) * (w1 - xi) + 0.25f * w2 * w2));
  const float env = expf(-0.5f * s2 * (w1 * w1 + 0.25f * w2 * w2));
  const float beta = expf(-0.5f * s2 * xi * xi);
  const float f = aa - beta * env;
  psi[i] = f;

  float v = fmaxf(f, 0.f);
  #pragma unroll
  for (int off = 32; off > 0; off >>= 1)
    v = fmaxf(v, __shfl_down(v, off, 64));
  __shared__ float wmax[4];
  const int lane = threadIdx.x & 63, wid = threadIdx.x >> 6;
  if (lane == 0) wmax[wid] = v;
  __syncthreads();
  if (threadIdx.x == 0) {
    const float mv = fmaxf(fmaxf(wmax[0], wmax[1]), fmaxf(wmax[2], wmax[3]));
    atomicMax(&fmax[bank * 8 + l], __float_as_int(mv));
  }
}

__global__ void norm_psi_kernel(float* psi, const int* fmax) {
  const long i = (long)blockIdx.x * 256 + threadIdx.x;
  if (i >= 2392064L) return;
  int bank = 0;
  while (i >= PSI_CUM[bank]) bank++;
  const long base = bank ? PSI_CUM[bank - 1] : 0;
  const long rem = i - base;
  const int m = PSI_MM[bank];
  const int l = (int)(rem / ((long)m * m));
  const float mx = fmaxf(__int_as_float(fmax[bank * 8 + l]), 1e-12f);
  psi[i] = psi[i] / mx;
}

__global__ void build_phi_kernel(float* phi) {
  const long i = (long)blockIdx.x * 256 + threadIdx.x;
  if (i >= 87040L) return;
  int rr; long base;
  if (i < 65536) { rr = 0; base = 0; }
  else if (i < 81920) { rr = 1; base = 65536; }
  else if (i < 86016) { rr = 2; base = 81920; }
  else { rr = 3; base = 86016; }
  const int m = 256 >> rr;
  const float sigma = 0.8f * (float)(1 << (4 - rr));
  const long pos = i - base;
  const int r = (int)(pos / m), c = (int)(pos % m);
  const float kx = 6.28318530717958647692f * dfreq_f(r, m);
  const float ky = 6.28318530717958647692f * dfreq_f(c, m);
  phi[i] = expf(-0.5f * sigma * sigma * (kx * kx + ky * ky));
}

// ---------------------------------------------------------------------------
// MLP
// ---------------------------------------------------------------------------
__global__ __launch_bounds__(256) void mlp1_kernel(const float* __restrict__ S,
                                                   const float* __restrict__ w1,
                                                   float* __restrict__ out1) {
  __shared__ float hs[16][256];
  const int o = blockIdx.x * 256 + threadIdx.x;
  const int ch = blockIdx.y;
  for (int idx = threadIdx.x; idx < 16 * 256; idx += 256) {
    const int b = idx >> 8, kk = idx & 255;
    hs[b][kk] = S[((long)b * 417 + ch) * 256 + kk];
  }
  __syncthreads();
  float acc[16];
  #pragma unroll
  for (int b = 0; b < 16; b++) acc[b] = 0.f;
  const float* wp = w1 + (long)ch * 256 * 1024 + o;
  for (int kk = 0; kk < 256; kk++) {
    const float w = wp[(long)kk * 1024];
    #pragma unroll
    for (int b = 0; b < 16; b++) acc[b] = fmaf(hs[b][kk], w, acc[b]);
  }
  #pragma unroll
  for (int b = 0; b < 16; b++) atomicAdd(&out1[b * 1024 + o], acc[b]);
}

__global__ void l1post_kernel(const float* out1, const float* b1, const float* g,
                              const float* bb, const float* mm, const float* vv, float* h1) {
  const int i = blockIdx.x * 256 + threadIdx.x;
  if (i < 16384) {
    const int o = i & 1023;
    const float xv = fmaxf(out1[i] + b1[o], 0.f);
    const float rs = (float)(1.0 / sqrt((double)vv[o] + 1e-5));
    h1[i] = (xv - mm[o]) * rs * g[o] + bb[o];
  }
}

__global__ __launch_bounds__(256) void mlp2_kernel(const float* h1, const float* w2, const float* b2,
                                                   const float* g, const float* bb, const float* mm,
                                                   const float* vv, float* h2) {
  __shared__ float hs[16][256];
  const int o = blockIdx.x * 256 + threadIdx.x;
  float acc[16];
  #pragma unroll
  for (int b = 0; b < 16; b++) acc[b] = 0.f;
  for (int kc = 0; kc < 4; kc++) {
    __syncthreads();
    for (int idx = threadIdx.x; idx < 16 * 256; idx += 256) {
      const int b = idx >> 8, kk = idx & 255;
      hs[b][kk] = h1[b * 1024 + kc * 256 + kk];
    }
    __syncthreads();
    for (int kk = 0; kk < 256; kk++) {
      const float w = w2[(long)(kc * 256 + kk) * 512 + o];
      #pragma unroll
      for (int b = 0; b < 16; b++) acc[b] = fmaf(hs[b][kk], w, acc[b]);
    }
  }
  const float bias = b2[o], gg = g[o], bbv = bb[o], mv = mm[o];
  const float rs = (float)(1.0 / sqrt((double)vv[o] + 1e-5));
  for (int b = 0; b < 16; b++) {
    const float xv = fmaxf(acc[b] + bias, 0.f);
    h2[b * 512 + o] = (xv - mv) * rs * gg + bbv;
  }
}

__global__ __launch_bounds__(128) void mlp3_kernel(const float* h2, const float* w3, const float* b3,
                                                   const float* g, const float* bb, const float* mm,
                                                   const float* vv, float* h3) {
  __shared__ float hs[16][256];
  const int o = threadIdx.x;
  float acc[16];
  #pragma unroll
  for (int b = 0; b < 16; b++) acc[b] = 0.f;
  for (int kc = 0; kc < 2; kc++) {
    __syncthreads();
    for (int idx = threadIdx.x; idx < 16 * 256; idx += 128) {
      const int b = idx >> 8, kk = idx & 255;
      hs[b][kk] = h2[b * 512 + kc * 256 + kk];
    }
    __syncthreads();
    for (int kk = 0; kk < 256; kk++) {
      const float w = w3[(kc * 256 + kk) * 128 + o];
      #pragma unroll
      for (int b = 0; b < 16; b++) acc[b] = fmaf(hs[b][kk], w, acc[b]);
    }
  }
  const float bias = b3[o], gg = g[o], bbv = bb[o], mv = mm[o];
  const float rs = (float)(1.0 / sqrt((double)vv[o] + 1e-5));
  for (int b = 0; b < 16; b++) {
    const float xv = fmaxf(acc[b] + bias, 0.f);
    h3[b * 128 + o] = (xv - mv) * rs * gg + bbv;
  }
}

__global__ void mlp4_kernel(const float* h3, const float* w4, const float* b4, float* out) {
  const int b = threadIdx.x;
  if (b < 16) {
    double a = 0.0;
    for (int k = 0; k < 128; k++) a += (double)h3[b * 128 + k] * (double)w4[k];
    out[b] = (float)(a + (double)b4[0]);
  }
}

// ---------------------------------------------------------------------------
// Orchestration
// ---------------------------------------------------------------------------
static RftParams rp0() {
  RftParams p;
  memset(&p, 0, sizeof(p));
  p.srcDiv = 1; p.filtMod = 1; p.chDiv = 1;
  p.scale = 1.f; p.sign = -1.f; p.m1 = 0;
  return p;
}

static TailParams tp0() {
  TailParams p;
  memset(&p, 0, sizeof(p));
  p.chDiv = 1;
  return p;
}

extern "C" void kernel_launch(void* const* d_in, const int* in_sizes, int n_in,
                              void* d_out, int out_size, void* d_ws, size_t ws_size,
                              hipStream_t stream) {
  (void)in_sizes; (void)n_in; (void)out_size; (void)ws_size;
  const float* x    = (const float*)d_in[0];
  const float* w1   = (const float*)d_in[1];
  const float* b1   = (const float*)d_in[2];
  const float* bn1g = (const float*)d_in[3];
  const float* bn1b = (const float*)d_in[4];
  const float* bn1m = (const float*)d_in[5];
  const float* bn1v = (const float*)d_in[6];
  const float* w2   = (const float*)d_in[7];
  const float* b2   = (const float*)d_in[8];
  const float* bn2g = (const float*)d_in[9];
  const float* bn2b = (const float*)d_in[10];
  const float* bn2m = (const float*)d_in[11];
  const float* bn2v = (const float*)d_in[12];
  const float* w3   = (const float*)d_in[13];
  const float* b3   = (const float*)d_in[14];
  const float* bn3g = (const float*)d_in[15];
  const float* bn3b = (const float*)d_in[16];
  const float* bn3m = (const float*)d_in[17];
  const float* bn3v = (const float*)d_in[18];
  const float* w4   = (const float*)d_in[19];
  const float* b4   = (const float*)d_in[20];

  char* ws = (char*)d_ws;
  const long MB = 1024L * 1024L;
  float2* XF   = (float2*)(ws);                //   8 MB
  float2* U1F  = (float2*)(ws + 8 * MB);       //  64 MB (reused across j1)
  float2* BUF1 = (float2*)(ws + 80 * MB);      // 160 MB
  float2* BUF2 = (float2*)(ws + 240 * MB);     // 160 MB
  float*  S    = (float*)(ws + 400 * MB);      // 16 x 417 x 256
  float*  PSI  = (float*)(ws + 408 * MB);      // 2392064 floats
  float*  PHI  = (float*)(ws + 418 * MB);      // 87040 floats
  int*    FMAX = (int*)(ws + 419 * MB);        // 56 slots
  float*  OUT1 = (float*)(ws + 419 * MB + 4096);
  float*  H1   = (float*)(ws + 419 * MB + 4096 + 65536);
  float*  H2   = (float*)(ws + 419 * MB + 4096 + 131072);
  float*  H3   = (float*)(ws + 419 * MB + 4096 + 196608);

  static const int psioff[7] = {0, 524288, 1048576, 1572864, 2097152, 2228224, 2359296};
  static const int phioff[4] = {0, 65536, 81920, 86016};

  // ---- filters ----
  hipMemsetAsync(FMAX, 0, 256, stream);
  build_psi_kernel<<<9344, 256, 0, stream>>>(PSI, FMAX);
  norm_psi_kernel<<<9344, 256, 0, stream>>>(PSI, FMAX);
  build_phi_kernel<<<340, 256, 0, stream>>>(PHI);

  // ---- Xf = fft2(x) ----
  { RftParams p = rp0(); p.inMode = IN_REAL; p.srcR = x; p.outMode = OUT_COMPLEX; p.dstC = BUF1; p.sign = -1.f; rft_go(256, 16, p, stream); }
  { RftParams p = rp0(); p.inMode = IN_COMPLEX; p.srcC = BUF1; p.outMode = OUT_COMPLEX; p.dstC = XF; p.sign = -1.f; rft_go(256, 16, p, stream); }

  // ---- s0 ----
  { RftParams p = rp0(); p.inMode = IN_MULFOLD; p.srcC = XF; p.filt = PHI + phioff[0]; p.m1 = 256; p.scale = 1.f / 65536.f; p.sign = 1.f; p.outMode = OUT_COMPLEX; p.dstC = BUF1; rft_go(16, 16, p, stream); }
  { RftParams p = rp0(); p.inMode = IN_COMPLEX; p.srcC = BUF1; p.sign = 1.f; p.outMode = OUT_REAL_S; p.dstR = S; p.chDiv = 1; p.chBase = 0; p.b0 = 0; rft_go(16, 16, p, stream); }

  for (int j1 = 0; j1 < 4; j1++) {
    const int m1 = 256 >> j1;
    const float isc1 = 1.f / (float)(m1 * m1);

    if (j1 <= 1) {
      // ---- u1 chain, R2-style global path (m1 = 256 / 128) ----
      { RftParams p = rp0(); p.inMode = IN_MULFOLD; p.srcC = XF; p.filt = PSI + psioff[j1]; p.m1 = 256; p.srcDiv = 8; p.filtMod = 8; p.scale = 1.f / 65536.f; p.sign = 1.f; p.outMode = OUT_COMPLEX; p.dstC = BUF1; rft_go(m1, 128, p, stream); }
      { RftParams p = rp0(); p.inMode = IN_COMPLEX; p.srcC = BUF1; p.sign = 1.f; p.outMode = OUT_ABS; p.dstR = (float*)BUF2; rft_go(m1, 128, p, stream); }
      { RftParams p = rp0(); p.inMode = IN_REAL; p.srcR = (const float*)BUF2; p.sign = -1.f; p.outMode = OUT_COMPLEX; p.dstC = BUF1; rft_go(m1, 128, p, stream); }
      { RftParams p = rp0(); p.inMode = IN_COMPLEX; p.srcC = BUF1; p.sign = -1.f; p.outMode = OUT_COMPLEX; p.dstC = U1F; rft_go(m1, 128, p, stream); }
      { RftParams p = rp0(); p.inMode = IN_MULFOLD; p.srcC = U1F; p.filt = PHI + phioff[j1]; p.m1 = m1; p.scale = isc1; p.sign = 1.f; p.outMode = OUT_COMPLEX; p.dstC = BUF1; rft_go(16, 128, p, stream); }
      { RftParams p = rp0(); p.inMode = IN_COMPLEX; p.srcC = BUF1; p.sign = 1.f; p.outMode = OUT_REAL_S; p.dstR = S; p.chDiv = 8; p.chBase = 1 + 8 * j1; p.b0 = 0; rft_go(16, 128, p, stream); }
    } else {
      // ---- fused u1: fold-from-XF + full chain + U1F (+S) in one kernel ----
      TailParams t = tp0();
      t.mode = 1; t.foldSrc = XF; t.foldFilt = PSI + psioff[j1];
      t.foldScale = 1.f / 65536.f; t.phi = PHI + phioff[j1]; t.sfScale = isc1;
      t.u1fOut = (j1 < 3) ? U1F : nullptr;   // j1=3 has no j2 branches
      t.S = S; t.chDiv = 8; t.chBase = 1 + 8 * j1;
      if (m1 == 64) tail_kernel<64><<<128, 256, 0, stream>>>(t);
      else          tail_kernel<32><<<128, 256, 0, stream>>>(t);
    }

    for (int j2 = j1 + 1; j2 < 4; j2++) {
      const int m2 = 256 >> j2;
      const float isc2 = 1.f / (float)(m2 * m2);
      int bank;
      if (j1 == 0) bank = j2;
      else if (j1 == 1) bank = j2 + 2;
      else bank = 6;
      const int pairIdx = (j1 == 0) ? (j2 - 1) : ((j1 == 1) ? (j2 + 1) : 5);
      const int chb = 33 + 64 * pairIdx;

      // pass-1: fold u1f through all 8 psi filters (source rows read once)
      { Fold8Params f; f.srcC = U1F; f.filt = PSI + psioff[bank]; f.dstC = BUF1; f.m1 = m1; f.scale = isc1; fold8_go(m2, 128, f, stream); }

      if (m2 <= 64) {
        // ---- fused tail: pass2+abs+fft2+phi-fold+ifft16+S in one kernel ----
        TailParams t = tp0();
        t.mode = 0; t.srcP1 = BUF1;
        t.phi = PHI + phioff[j2]; t.sfScale = isc2;
        t.S = S; t.chDiv = 64; t.chBase = chb;
        if (m2 == 64) tail_kernel<64><<<1024, 256, 0, stream>>>(t);
        else          tail_kernel<32><<<1024, 256, 0, stream>>>(t);
      } else {
        // (0,1): m2=128 doesn't fit in LDS; global chain
        { RftParams p = rp0(); p.inMode = IN_COMPLEX; p.srcC = BUF1; p.sign = 1.f; p.outMode = OUT_ABS; p.dstR = (float*)BUF2; rft_go(m2, 1024, p, stream); }
        { RftParams p = rp0(); p.inMode = IN_REAL; p.srcR = (const float*)BUF2; p.sign = -1.f; p.outMode = OUT_COMPLEX; p.dstC = BUF1; rft_go(m2, 1024, p, stream); }
        { RftParams p = rp0(); p.inMode = IN_COMPLEX; p.srcC = BUF1; p.sign = -1.f; p.outMode = OUT_COMPLEX; p.dstC = BUF2; rft_go(m2, 1024, p, stream); }
        { RftParams p = rp0(); p.inMode = IN_MULFOLD; p.srcC = BUF2; p.filt = PHI + phioff[j2]; p.m1 = m2; p.scale = isc2; p.sign = 1.f; p.outMode = OUT_COMPLEX; p.dstC = BUF1; rft_go(16, 1024, p, stream); }
        { RftParams p = rp0(); p.inMode = IN_COMPLEX; p.srcC = BUF1; p.sign = 1.f; p.outMode = OUT_REAL_S; p.dstR = S; p.chDiv = 64; p.chBase = chb; p.b0 = 0; rft_go(16, 1024, p, stream); }
      }
    }
  }

  // ---- MLP ----
  hipMemsetAsync(OUT1, 0, 16 * 1024 * 4, stream);
  mlp1_kernel<<<dim3(4, 417), 256, 0, stream>>>(S, w1, OUT1);
  l1post_kernel<<<64, 256, 0, stream>>>(OUT1, b1, bn1g, bn1b, bn1m, bn1v, H1);
  mlp2_kernel<<<2, 256, 0, stream>>>(H1, w2, b2, bn2g, bn2b, bn2m, bn2v, H2);
  mlp3_kernel<<<1, 128, 0, stream>>>(H2, w3, b3, bn3g, bn3b, bn3m, bn3v, H3);
  mlp4_kernel<<<1, 64, 0, stream>>>(H3, w4, b4, (float*)d_out);
}